// Round 7
// baseline (191.758 us; speedup 1.0000x reference)
//
#include <hip/hip_runtime.h>

// LinearTextEmbedding: out[c][x][y] = (|bits[(x*1024+y) % 4096]| > 0.5) ? 1 : 0
// broadcast over 48 channels. Flat: out[o] = f(bits[o & 4095]).
//
// Pure write-bandwidth problem: 201.3 MB out, 16 KB in.
//
// Round-2 lesson: nontemporal stores regress ~35% (defeat L2/L3 write batching).
// Round-3/6 lesson: store structure (ILP depth, stride, launch count) is
//   IRRELEVANT — 1-store/thread, 8MiB-stride, contiguous-ILP all land at
//   65-74 us residual. The graph is an HBM write conveyor: 768 MiB ws-poison
//   + ~192 MiB out-poison + 192 MiB output = 1152 MiB @ 6.68 TB/s = 172 us
//   ~= the measured 187 us total. Only traffic reduction can win.
//
// This version: DESCENDING sweep to coalesce with still-dirty poison.
//   The out-buffer poison (192 MiB < 256 MiB L3) is dirty in Infinity Cache
//   when our kernel starts. Overwriting a line while still dirty cancels the
//   poison's HBM writeback. Background drain evicts oldest (lowest) addresses
//   first, so we sweep DESCENDING (youngest first) to win the eviction races.
//   Block b' = GRID-1-b owns contiguous 96 KB; 24 independent stores/thread.

typedef float f4 __attribute__((ext_vector_type(4)));

#define OUT_ELEMS (48u * 1024u * 1024u)   // 50331648 floats
#define N4        (OUT_ELEMS / 4u)        // 12582912 float4 stores
#define BLOCK     256u
#define ITERS     24u                     // stores per thread
#define SEG       (BLOCK * ITERS)         // 6144 float4s = 96 KB per block
#define GRID      (N4 / SEG)              // 2048 blocks = 8 per CU, one generation

static_assert(GRID * SEG == N4, "exact cover, no tail");
static_assert((SEG * 4u) % 4096u == 0u, "block segment = whole periods");
static_assert((BLOCK * 4u * 4u) == 4096u, "4 iters span one period (k&3)");

__global__ __launch_bounds__(BLOCK) void
LinearTextEmbedding_57604101374655_kernel(const float* __restrict__ bits,
                                          f4* __restrict__ out) {
    unsigned t = threadIdx.x;
    // descending block->segment map: later-dispatched blocks get LOWER
    // addresses; earliest blocks hit the highest (youngest-dirty) lines.
    unsigned base = (GRID - 1u - blockIdx.x) * SEG;

    // float offset within a block segment for iter k, lane t: 1024*k + 4*t.
    // mod 4096 -> depends only on k&3: bits float4 index (t + 256*(k&3)) & 1023.
    const f4* b4 = reinterpret_cast<const f4*>(bits);
    f4 v[4];
#pragma unroll
    for (unsigned j = 0; j < 4; ++j) {
        f4 b = b4[(t + 256u * j) & 1023u];
        v[j].x = (fabsf(b.x) > 0.5f) ? 1.0f : 0.0f;
        v[j].y = (fabsf(b.y) > 0.5f) ? 1.0f : 0.0f;
        v[j].z = (fabsf(b.z) > 0.5f) ? 1.0f : 0.0f;
        v[j].w = (fabsf(b.w) > 0.5f) ? 1.0f : 0.0f;
    }

    f4* p = out + base + t;
#pragma unroll
    for (unsigned k = 0; k < ITERS; ++k) {
        p[k * BLOCK] = v[k & 3u];   // contiguous 4 KB/wave/iter
    }
}

extern "C" void kernel_launch(void* const* d_in, const int* in_sizes, int n_in,
                              void* d_out, int out_size, void* d_ws, size_t ws_size,
                              hipStream_t stream) {
    const float* bits = (const float*)d_in[0];
    f4* out = (f4*)d_out;
    LinearTextEmbedding_57604101374655_kernel<<<GRID, BLOCK, 0, stream>>>(bits, out);
}

// Round 8
// 187.427 us; speedup vs baseline: 1.0231x; 1.0231x over previous
//
#include <hip/hip_runtime.h>

// LinearTextEmbedding: out[c][x][y] = (|bits[(x*1024+y) % 4096]| > 0.5) ? 1 : 0
// broadcast over 48 channels. Flat: out[o] = f(bits[o & 4095]) since both the
// image size (1048576) and channel stride are multiples of 4096.
//
// Pure write-bandwidth problem: 201.3 MB out, 16 KB in.
//
// ROOFLINE NOTE (rounds 0-7): this simple one-store-per-thread form IS the
// floor. The timed graph's HBM write traffic is ~1152 MiB (768 MiB ws-poison
// + ~192 MiB out-poison + 192 MiB output); at the measured ~6.65 TB/s device
// write ceiling that is ~181 us + launch gaps ~= the 187 us measured total.
// Verified-null levers: store ILP (24-deep periodic stores, +5 us), launch
// count (2048 vs 49152 blocks, null), contiguous/strided/descending sweep
// order (null), dirty-overwrite coalescing via descending sweep (null).
// Verified-negative: __builtin_nontemporal_store (-22 us, defeats L2/L3
// write batching). No instruction-stream change reduces bytes on the belt.

#define OUT_ELEMS (48u * 1024u * 1024u)   // 50331648 floats
#define N4        (OUT_ELEMS / 4u)        // 12582912 float4 stores

__global__ __launch_bounds__(256) void
LinearTextEmbedding_57604101374655_kernel(const float* __restrict__ bits,
                                          float4* __restrict__ out) {
    unsigned t = blockIdx.x * blockDim.x + threadIdx.x;
    if (t >= N4) return;
    // bit index for the 4 floats this thread writes: (t*4) & 4095, aligned to 4,
    // never straddles the 4096 wrap -> single float4 load at index t & 1023.
    float4 b = reinterpret_cast<const float4*>(bits)[t & 1023u];
    float4 v;
    v.x = (fabsf(b.x) > 0.5f) ? 1.0f : 0.0f;
    v.y = (fabsf(b.y) > 0.5f) ? 1.0f : 0.0f;
    v.z = (fabsf(b.z) > 0.5f) ? 1.0f : 0.0f;
    v.w = (fabsf(b.w) > 0.5f) ? 1.0f : 0.0f;
    out[t] = v;
}

extern "C" void kernel_launch(void* const* d_in, const int* in_sizes, int n_in,
                              void* d_out, int out_size, void* d_ws, size_t ws_size,
                              hipStream_t stream) {
    const float* bits = (const float*)d_in[0];
    float4* out = (float4*)d_out;
    const int block = 256;
    const int grid = (N4 + block - 1) / block;   // 49152 blocks
    LinearTextEmbedding_57604101374655_kernel<<<grid, block, 0, stream>>>(bits, out);
}